// Round 4
// baseline (1174.833 us; speedup 1.0000x reference)
//
#include <hip/hip_runtime.h>

#define EPS 1e-12f
#define NSCAN 256   // scan blocks/threads
#define DMAX 16     // max CSR entries held in registers (deg ~ Poisson(6))

// ---------------------------------------------------------------------------
// Pipeline: memset cursor -> count -> scan(3 kernels) -> fill(int2 CSR, atomicSub)
//           -> gather_all_batches (thread-per-vertex, batch inner loop,
//              CSR entries in registers, nontemporal output stores)
// CSR entry at corner v of face (i0,i1,i2) stores the other two indices (a,b)
// in cyclic order; contribution (A-v)x(B-v) equals the reference's
// cross(v2-v1, v0-v1) at every corner (cyclic identity, verified R2/R3).
// ---------------------------------------------------------------------------

__global__ void count_kernel(const int* __restrict__ faces, int* __restrict__ counts, int F) {
    int f = blockIdx.x * blockDim.x + threadIdx.x;
    if (f >= F) return;
    atomicAdd(&counts[faces[3 * f + 0]], 1);
    atomicAdd(&counts[faces[3 * f + 1]], 1);
    atomicAdd(&counts[faces[3 * f + 2]], 1);
}

__global__ __launch_bounds__(NSCAN) void scan_partials(const int* __restrict__ counts,
                                                       int* __restrict__ partials,
                                                       int V, int chunk) {
    int b = blockIdx.x, t = threadIdx.x;
    int bstart = b * chunk;
    int bend = min(bstart + chunk, V);
    int s = 0;
    for (int i = bstart + t; i < bend; i += NSCAN) s += counts[i];
    __shared__ int red[NSCAN];
    red[t] = s;
    __syncthreads();
    for (int o = NSCAN / 2; o > 0; o >>= 1) {
        if (t < o) red[t] += red[t + o];
        __syncthreads();
    }
    if (t == 0) partials[b] = red[0];
}

__global__ __launch_bounds__(NSCAN) void scan_top(int* __restrict__ partials) {
    __shared__ int s[NSCAN];
    int t = threadIdx.x;
    int v = partials[t];
    s[t] = v;
    __syncthreads();
    for (int o = 1; o < NSCAN; o <<= 1) {
        int u = (t >= o) ? s[t - o] : 0;
        __syncthreads();
        s[t] += u;
        __syncthreads();
    }
    partials[t] = s[t] - v;  // exclusive
}

__global__ __launch_bounds__(NSCAN) void scan_final(const int* __restrict__ counts,
                                                    const int* __restrict__ partials,
                                                    int* __restrict__ offsets,
                                                    int V, int chunk) {
    int b = blockIdx.x, t = threadIdx.x;
    int bstart = b * chunk;
    int bend = min(bstart + chunk, V);
    int sc = (chunk + NSCAN - 1) / NSCAN;
    int tstart = bstart + t * sc;
    int tend = min(tstart + sc, bend);
    int c[8];
    int n = 0, tsum = 0;
    for (int i = tstart; i < tend; i++) {
        int cv = counts[i];
        c[n++] = cv;
        tsum += cv;
    }
    __shared__ int s[NSCAN];
    s[t] = tsum;
    __syncthreads();
    for (int o = 1; o < NSCAN; o <<= 1) {
        int u = (t >= o) ? s[t - o] : 0;
        __syncthreads();
        s[t] += u;
        __syncthreads();
    }
    int run = partials[b] + s[t] - tsum;  // exclusive base for this thread
    n = 0;
    for (int i = tstart; i < tend; i++) {
        offsets[i] = run;
        run += c[n++];
    }
    if (bend == V && tend == V) offsets[V] = run;
}

// fill: cursor holds counts; atomicSub gives unique slot without re-zeroing
__global__ void fill_kernel(const int* __restrict__ faces,
                            const int* __restrict__ offsets,
                            int* __restrict__ cursor,
                            int2* __restrict__ csr, int F) {
    int f = blockIdx.x * blockDim.x + threadIdx.x;
    if (f >= F) return;
    int i0 = faces[3 * f + 0];
    int i1 = faces[3 * f + 1];
    int i2 = faces[3 * f + 2];
    int vs[3] = {i0, i1, i2};
    int as[3] = {i1, i2, i0};
    int bs[3] = {i2, i0, i1};
#pragma unroll
    for (int c = 0; c < 3; c++) {
        int v = vs[c];
        int old = atomicSub(&cursor[v], 1);
        int pos = offsets[v] + old - 1;
        csr[pos] = make_int2(as[c], bs[c]);
    }
}

// One thread per vertex; inner loop over all batches. CSR entries cached in
// registers across batches; all waves co-resident -> per-XCD L2 working set
// is ~one batch's 2.4 MB vertex array at any instant.
__global__ __launch_bounds__(128) void gather_all_batches(
        const float* __restrict__ verts,
        const int* __restrict__ offsets,
        const int2* __restrict__ csr,
        float* __restrict__ out,
        int V, int B) {
    int v = blockIdx.x * 128 + threadIdx.x;
    if (v >= V) return;

    int s = offsets[v];
    int e = offsets[v + 1];
    int deg = e - s;
    int dreg = min(deg, DMAX);

    int2 ent[DMAX];
#pragma unroll
    for (int k = 0; k < DMAX; k++) {
        if (k < dreg) ent[k] = csr[s + k];
    }

    for (int b = 0; b < B; b++) {
        const float* vb = verts + (size_t)b * V * 3;
        float vx = vb[3 * v + 0], vy = vb[3 * v + 1], vz = vb[3 * v + 2];
        float ax = 0.f, ay = 0.f, az = 0.f;
#pragma unroll
        for (int k = 0; k < DMAX; k++) {
            if (k < dreg) {
                int2 p = ent[k];
                float Ax = vb[3 * p.x + 0], Ay = vb[3 * p.x + 1], Az = vb[3 * p.x + 2];
                float Bx = vb[3 * p.y + 0], By = vb[3 * p.y + 1], Bz = vb[3 * p.y + 2];
                float aX = Ax - vx, aY = Ay - vy, aZ = Az - vz;
                float bX = Bx - vx, bY = By - vy, bZ = Bz - vz;
                ax += aY * bZ - aZ * bY;
                ay += aZ * bX - aX * bZ;
                az += aX * bY - aY * bX;
            }
        }
        for (int k = DMAX; k < deg; k++) {  // rare overflow (deg > 16)
            int2 p = csr[s + k];
            float Ax = vb[3 * p.x + 0], Ay = vb[3 * p.x + 1], Az = vb[3 * p.x + 2];
            float Bx = vb[3 * p.y + 0], By = vb[3 * p.y + 1], Bz = vb[3 * p.y + 2];
            float aX = Ax - vx, aY = Ay - vy, aZ = Az - vz;
            float bX = Bx - vx, bY = By - vy, bZ = Bz - vz;
            ax += aY * bZ - aZ * bY;
            ay += aZ * bX - aX * bZ;
            az += aX * bY - aY * bX;
        }
        float sc = rsqrtf(fmaxf(ax * ax + ay * ay + az * az, EPS));
        size_t o = ((size_t)b * V + v) * 3;
        __builtin_nontemporal_store(ax * sc, &out[o + 0]);
        __builtin_nontemporal_store(ay * sc, &out[o + 1]);
        __builtin_nontemporal_store(az * sc, &out[o + 2]);
    }
}

extern "C" void kernel_launch(void* const* d_in, const int* in_sizes, int n_in,
                              void* d_out, int out_size, void* d_ws, size_t ws_size,
                              hipStream_t stream) {
    const float* verts = (const float*)d_in[0];
    const int* faces = (const int*)d_in[1];
    float* out = (float*)d_out;

    const int V = 200000;
    const int F = in_sizes[1] / 3;           // 400000
    const int B = in_sizes[0] / (3 * V);     // 32

    // workspace layout: offsets[V+1] | cursor[V] | partials[NSCAN] | csr[3F] (int2)
    int* offsets = (int*)d_ws;
    int* cursor = offsets + (V + 1);
    int* partials = cursor + V;
    int2* csr = (int2*)(partials + NSCAN);

    const int chunk = (V + NSCAN - 1) / NSCAN;  // 782

    hipMemsetAsync(cursor, 0, (size_t)V * 4, stream);
    count_kernel<<<(F + 255) / 256, 256, 0, stream>>>(faces, cursor, F);
    scan_partials<<<NSCAN, NSCAN, 0, stream>>>(cursor, partials, V, chunk);
    scan_top<<<1, NSCAN, 0, stream>>>(partials);
    scan_final<<<NSCAN, NSCAN, 0, stream>>>(cursor, partials, offsets, V, chunk);
    fill_kernel<<<(F + 255) / 256, 256, 0, stream>>>(faces, offsets, cursor, csr, F);

    int nblk = (V + 127) / 128;  // 1563 blocks, all co-resident
    gather_all_batches<<<nblk, 128, 0, stream>>>(verts, offsets, csr, out, V, B);
}

// Round 5
// 908.109 us; speedup vs baseline: 1.2937x; 1.2937x over previous
//
#include <hip/hip_runtime.h>

#define EPS 1e-12f
#define NSCAN 256   // scan blocks/threads

typedef int v2i __attribute__((ext_vector_type(2)));

// ---------------------------------------------------------------------------
// Pipeline: memset cursor -> count -> scan(3) -> fill(int2 CSR, atomicSub)
//           -> gather (grid (vblocks, B), batch-major dispatch, occupancy
//              capped to 3 blocks/CU via 48 KB dynamic LDS so only ~one
//              batch's 2.4 MB vertex array is live per XCD L2; CSR + output
//              use nontemporal accesses so the vertex array isn't evicted).
// CSR entry at corner v of face (i0,i1,i2) stores the other two indices (a,b)
// in cyclic order; contribution (A-v)x(B-v) equals the reference's
// cross(v2-v1, v0-v1) at every corner (cyclic identity, verified R2/R3).
// ---------------------------------------------------------------------------

__global__ void count_kernel(const int* __restrict__ faces, int* __restrict__ counts, int F) {
    int f = blockIdx.x * blockDim.x + threadIdx.x;
    if (f >= F) return;
    atomicAdd(&counts[faces[3 * f + 0]], 1);
    atomicAdd(&counts[faces[3 * f + 1]], 1);
    atomicAdd(&counts[faces[3 * f + 2]], 1);
}

__global__ __launch_bounds__(NSCAN) void scan_partials(const int* __restrict__ counts,
                                                       int* __restrict__ partials,
                                                       int V, int chunk) {
    int b = blockIdx.x, t = threadIdx.x;
    int bstart = b * chunk;
    int bend = min(bstart + chunk, V);
    int s = 0;
    for (int i = bstart + t; i < bend; i += NSCAN) s += counts[i];
    __shared__ int red[NSCAN];
    red[t] = s;
    __syncthreads();
    for (int o = NSCAN / 2; o > 0; o >>= 1) {
        if (t < o) red[t] += red[t + o];
        __syncthreads();
    }
    if (t == 0) partials[b] = red[0];
}

__global__ __launch_bounds__(NSCAN) void scan_top(int* __restrict__ partials) {
    __shared__ int s[NSCAN];
    int t = threadIdx.x;
    int v = partials[t];
    s[t] = v;
    __syncthreads();
    for (int o = 1; o < NSCAN; o <<= 1) {
        int u = (t >= o) ? s[t - o] : 0;
        __syncthreads();
        s[t] += u;
        __syncthreads();
    }
    partials[t] = s[t] - v;  // exclusive
}

__global__ __launch_bounds__(NSCAN) void scan_final(const int* __restrict__ counts,
                                                    const int* __restrict__ partials,
                                                    int* __restrict__ offsets,
                                                    int V, int chunk) {
    int b = blockIdx.x, t = threadIdx.x;
    int bstart = b * chunk;
    int bend = min(bstart + chunk, V);
    int sc = (chunk + NSCAN - 1) / NSCAN;
    int tstart = bstart + t * sc;
    int tend = min(tstart + sc, bend);
    int c[8];
    int n = 0, tsum = 0;
    for (int i = tstart; i < tend; i++) {
        int cv = counts[i];
        c[n++] = cv;
        tsum += cv;
    }
    __shared__ int s[NSCAN];
    s[t] = tsum;
    __syncthreads();
    for (int o = 1; o < NSCAN; o <<= 1) {
        int u = (t >= o) ? s[t - o] : 0;
        __syncthreads();
        s[t] += u;
        __syncthreads();
    }
    int run = partials[b] + s[t] - tsum;  // exclusive base for this thread
    n = 0;
    for (int i = tstart; i < tend; i++) {
        offsets[i] = run;
        run += c[n++];
    }
    if (bend == V && tend == V) offsets[V] = run;
}

__global__ void fill_kernel(const int* __restrict__ faces,
                            const int* __restrict__ offsets,
                            int* __restrict__ cursor,
                            v2i* __restrict__ csr, int F) {
    int f = blockIdx.x * blockDim.x + threadIdx.x;
    if (f >= F) return;
    int i0 = faces[3 * f + 0];
    int i1 = faces[3 * f + 1];
    int i2 = faces[3 * f + 2];
    int vs[3] = {i0, i1, i2};
    int as[3] = {i1, i2, i0};
    int bs[3] = {i2, i0, i1};
#pragma unroll
    for (int c = 0; c < 3; c++) {
        int v = vs[c];
        int old = atomicSub(&cursor[v], 1);
        int pos = offsets[v] + old - 1;
        v2i e; e.x = as[c]; e.y = bs[c];
        csr[pos] = e;
    }
}

// grid (ceil(V/256), B); y (batch) is the slowest dispatch dimension, so at
// ~768 resident blocks (48 KB dynamic-LDS cap = 3 blocks/CU) only ~one
// batch's vertex array is hot per XCD L2. CSR is nontemporal (evict-first)
// so its 9.6 MB/batch stream doesn't evict the 2.4 MB vertex array; output
// stores are nontemporal for the same reason.
__global__ __launch_bounds__(256) void gather_kernel(const float* __restrict__ verts,
                                                     const int* __restrict__ offsets,
                                                     const v2i* __restrict__ csr,
                                                     float* __restrict__ out, int V) {
    int v = blockIdx.x * 256 + threadIdx.x;
    if (v >= V) return;
    int b = blockIdx.y;

    const float* vb = verts + (size_t)b * V * 3;
    float vx = vb[3 * v + 0], vy = vb[3 * v + 1], vz = vb[3 * v + 2];

    int s = offsets[v];
    int e = offsets[v + 1];
    float ax = 0.f, ay = 0.f, az = 0.f;
    for (int k = s; k < e; k++) {
        v2i p = __builtin_nontemporal_load(&csr[k]);
        const float* A = vb + 3 * (size_t)p.x;
        const float* Bv = vb + 3 * (size_t)p.y;
        float aX = A[0] - vx, aY = A[1] - vy, aZ = A[2] - vz;
        float bX = Bv[0] - vx, bY = Bv[1] - vy, bZ = Bv[2] - vz;
        ax += aY * bZ - aZ * bY;
        ay += aZ * bX - aX * bZ;
        az += aX * bY - aY * bX;
    }
    float sc = rsqrtf(fmaxf(ax * ax + ay * ay + az * az, EPS));
    size_t o = ((size_t)b * V + v) * 3;
    __builtin_nontemporal_store(ax * sc, &out[o + 0]);
    __builtin_nontemporal_store(ay * sc, &out[o + 1]);
    __builtin_nontemporal_store(az * sc, &out[o + 2]);
}

extern "C" void kernel_launch(void* const* d_in, const int* in_sizes, int n_in,
                              void* d_out, int out_size, void* d_ws, size_t ws_size,
                              hipStream_t stream) {
    const float* verts = (const float*)d_in[0];
    const int* faces = (const int*)d_in[1];
    float* out = (float*)d_out;

    const int V = 200000;
    const int F = in_sizes[1] / 3;           // 400000
    const int B = in_sizes[0] / (3 * V);     // 32

    // workspace layout: offsets[V+1] | cursor[V] | partials[NSCAN] | csr[3F] (int2)
    int* offsets = (int*)d_ws;
    int* cursor = offsets + (V + 1);
    int* partials = cursor + V;
    v2i* csr = (v2i*)(partials + NSCAN);

    const int chunk = (V + NSCAN - 1) / NSCAN;  // 782

    hipMemsetAsync(cursor, 0, (size_t)V * 4, stream);
    count_kernel<<<(F + 255) / 256, 256, 0, stream>>>(faces, cursor, F);
    scan_partials<<<NSCAN, NSCAN, 0, stream>>>(cursor, partials, V, chunk);
    scan_top<<<1, NSCAN, 0, stream>>>(partials);
    scan_final<<<NSCAN, NSCAN, 0, stream>>>(cursor, partials, offsets, V, chunk);
    fill_kernel<<<(F + 255) / 256, 256, 0, stream>>>(faces, offsets, cursor, csr, F);

    dim3 ggrid((V + 255) / 256, B);  // y = batch, slowest dispatch dim
    // 48 KB dynamic LDS caps occupancy at 3 blocks/CU (160 KB LDS / 48 KB):
    // 768 resident blocks ~= one batch's 782 blocks -> one batch in flight.
    gather_kernel<<<ggrid, 256, 48 * 1024, stream>>>(verts, offsets, csr, out, V);
}